// Round 9
// baseline (116.014 us; speedup 1.0000x reference)
//
#include <hip/hip_runtime.h>

// CIN (xDeepFM) fused kernel for MI355X (gfx950), round 9.
// BOTH layers reassociated per field m:
//   h0[o,c] = relu(b0 + sum_m x[m,c] * (W0_m(256x48) @ x(48x64))[o,c])
//   out1[o,c] = relu(b1 + sum_m x[m,c] * (W1_m(128x128) @ h(128x64))[o,c])
// The per-m scale folds into the MFMA B-operand (bz = Bfrag * xm, v_pk_mul_f16),
// B-frags (x / h) live in REGISTERS -> the K-loops touch ZERO LDS.
// m is wave-uniform -> xm extracted from register chunks with static indices.
// MFMA: 32x32x16 f16 (L0 K pads 39->48). Weights repacked per-wave-contiguous,
// 2-deep branchless prefetch. 8 waves: L0 = 8 row-tiles; L1 = 4 row-tiles x
// 2 K-halves (combined via LDS). 512 blocks x 512 thr, 2 blocks/CU.

typedef _Float16 f16x8 __attribute__((ext_vector_type(8)));
typedef float f32x16 __attribute__((ext_vector_type(16)));

#define NB 2
#define NBLK 512
#define THREADS 512

__global__ __launch_bounds__(256) void prep_kernel(
    const float* __restrict__ w0, const float* __restrict__ w1,
    _Float16* __restrict__ w0r, _Float16* __restrict__ w1r) {
  int stride = gridDim.x * blockDim.x;
  int tid = blockIdx.x * blockDim.x + threadIdx.x;
  // w0r[((m*8+w)*3+ks)*512 + l*8 + j] = W0[o=w*32+(l&31)][m*39 + n],
  //   n = ks*16 + (l>>5)*8 + j  (zero if n>=39 or m>=39)
  const int n0 = 40 * 8 * 3 * 512;
  for (int idx = tid; idx < n0; idx += stride) {
    int j = idx & 7, l = (idx >> 3) & 63, f = idx >> 9;
    int mw = f / 3, ks = f - mw * 3;
    int w8 = mw & 7, m = mw >> 3;
    int o = w8 * 32 + (l & 31);
    int n = ks * 16 + ((l >> 5) << 3) + j;
    float v = (m < 39 && n < 39) ? w0[o * 1521 + m * 39 + n] : 0.f;
    w0r[idx] = (_Float16)v;
  }
  // w1r[(((m*2+kh)*4+rt)*4+ks)*512 + l*8 + j] = W1[o=rt*32+(l&31)][m*128 + k],
  //   k = kh*64 + ks*16 + (l>>5)*8 + j   (zero if m>=39)
  const int n1 = 40 * 2 * 4 * 4 * 512;
  for (int idx = tid; idx < n1; idx += stride) {
    int j = idx & 7, l = (idx >> 3) & 63, ks = (idx >> 9) & 3;
    int rt = (idx >> 11) & 3, kh = (idx >> 13) & 1, m = idx >> 14;
    int o = rt * 32 + (l & 31);
    int k = kh * 64 + ks * 16 + ((l >> 5) << 3) + j;
    float v = (m < 39) ? w1[o * 4992 + m * 128 + k] : 0.f;
    w1r[idx] = (_Float16)v;
  }
}

__global__ __launch_bounds__(512, 2) void cin_kernel(
    const float* __restrict__ x,
    const _Float16* __restrict__ w0r, const float* __restrict__ b0,
    const _Float16* __restrict__ w1r, const float* __restrict__ b1,
    float* __restrict__ out) {
  // LDS: 7168 + 17408 + 33792 = 58368 B -> 2 blocks/CU
  __shared__ __align__(16) _Float16 xs[64 * 56];   // [c][56], slots 39..55 = 0
  __shared__ __align__(16) _Float16 h1[64 * 136];  // [c][136], h1a channels 0..127
  __shared__ __align__(16) float red[4 * 32 * 66]; // L1 K-half exchange

  const int t = threadIdx.x;
  const int bb = blockIdx.x * NB;
  const int w = t >> 6;        // wave 0..7
  const int l = t & 63;
  const int l31 = l & 31;
  const int hi = l >> 5;

  // ---- stage x -> xs[c=(b,d)][m], f16, zero-padded to 56 ----
  for (int idx = t; idx < NB * 39 * 32; idx += THREADS) {
    int b = idx / 1248; int rem = idx - b * 1248;
    int m = rem >> 5; int d = rem & 31;
    xs[(b * 32 + d) * 56 + m] = (_Float16)x[(bb + b) * 1248 + rem];
  }
  for (int idx = t; idx < 64 * 17; idx += THREADS) {
    int c = idx / 17; int mm = 39 + (idx - c * 17);
    xs[c * 56 + mm] = (_Float16)0.f;
  }
  __syncthreads();

  // ================= LAYER 0 =================
  // persistent B source: xf[ct][ks] = x[n = ks*16+hi*8+j][c = ct*32+l31]
  f16x8 xf[2][3];
#pragma unroll
  for (int ct = 0; ct < 2; ++ct)
#pragma unroll
    for (int ks = 0; ks < 3; ++ks)
      xf[ct][ks] = *(const f16x8*)&xs[(ct * 32 + l31) * 56 + ks * 16 + hi * 8];

  f32x16 acc0[2] = {};
  const _Float16* pw0 = w0r + w * 1536 + l * 8;
  f16x8 wfA[3], wfB[3];
  auto ldW0 = [&](int m, f16x8 (&wf)[3]) {
    const _Float16* p = pw0 + m * 12288;
#pragma unroll
    for (int ks = 0; ks < 3; ++ks) wf[ks] = *(const f16x8*)(p + ks * 512);
  };
  ldW0(0, wfA); ldW0(1, wfB);

  f16x8 xmkC[2], xmkN[2];
#pragma unroll
  for (int ct = 0; ct < 2; ++ct) xmkC[ct] = *(const f16x8*)&xs[(ct * 32 + l31) * 56];

  for (int g = 0; g < 5; ++g) {
    int gn = (g < 4) ? g + 1 : 4;
#pragma unroll
    for (int ct = 0; ct < 2; ++ct)
      xmkN[ct] = *(const f16x8*)&xs[(ct * 32 + l31) * 56 + gn * 8];
#pragma unroll
    for (int jj = 0; jj < 8; jj += 2) {
      int m = g * 8 + jj;
#pragma unroll
      for (int ct = 0; ct < 2; ++ct) {
        _Float16 xm = xmkC[ct][jj];
#pragma unroll
        for (int ks = 0; ks < 3; ++ks) {
          f16x8 bz = xf[ct][ks] * xm;
          acc0[ct] = __builtin_amdgcn_mfma_f32_32x32x16_f16(wfA[ks], bz, acc0[ct], 0, 0, 0);
        }
      }
      { int mp = (m + 2 > 39) ? 39 : m + 2; ldW0(mp, wfA); }
#pragma unroll
      for (int ct = 0; ct < 2; ++ct) {
        _Float16 xm = xmkC[ct][jj + 1];
#pragma unroll
        for (int ks = 0; ks < 3; ++ks) {
          f16x8 bz = xf[ct][ks] * xm;
          acc0[ct] = __builtin_amdgcn_mfma_f32_32x32x16_f16(wfB[ks], bz, acc0[ct], 0, 0, 0);
        }
      }
      { int mp = (m + 3 > 39) ? 39 : m + 3; ldW0(mp, wfB); }
    }
    xmkC[0] = xmkN[0]; xmkC[1] = xmkN[1];
  }

  // ---- epilogue 0: C/D row = (reg&3)+8*(reg>>2)+4*hi, col = l31 ----
  if (w < 4) {
#pragma unroll
    for (int ct = 0; ct < 2; ++ct)
#pragma unroll
      for (int reg = 0; reg < 16; ++reg) {
        int o = w * 32 + (reg & 3) + 8 * (reg >> 2) + 4 * hi;
        float v = fmaxf(acc0[ct][reg] + b0[o], 0.f);
        h1[(ct * 32 + l31) * 136 + o] = (_Float16)v;
      }
  } else {
#pragma unroll
    for (int ct = 0; ct < 2; ++ct)
#pragma unroll
      for (int reg = 0; reg < 16; ++reg) {
        int o = w * 32 + (reg & 3) + 8 * (reg >> 2) + 4 * hi;  // 128..255
        float v = fmaxf(acc0[ct][reg] + b0[o], 0.f);
        v += __shfl_xor(v, 1); v += __shfl_xor(v, 2); v += __shfl_xor(v, 4);
        v += __shfl_xor(v, 8); v += __shfl_xor(v, 16);
        if (l31 == 0) out[(bb + ct) * 256 + (o - 128)] = v;
      }
  }
  __syncthreads();

  // ================= LAYER 1 (4 row-tiles x 2 K-halves) =================
  const int rt = w >> 1, kh = w & 1;
  f16x8 hf[2][4];
#pragma unroll
  for (int ct = 0; ct < 2; ++ct)
#pragma unroll
    for (int ks = 0; ks < 4; ++ks)
      hf[ct][ks] = *(const f16x8*)&h1[(ct * 32 + l31) * 136 + kh * 64 + ks * 16 + hi * 8];

  f32x16 acc1[2] = {};
  const _Float16* pw1 = w1r + (kh * 4 + rt) * 2048 + l * 8;
  f16x8 vfA[4], vfB[4];
  auto ldW1 = [&](int m, f16x8 (&wf)[4]) {
    const _Float16* p = pw1 + m * 16384;
#pragma unroll
    for (int ks = 0; ks < 4; ++ks) wf[ks] = *(const f16x8*)(p + ks * 512);
  };
  ldW1(0, vfA); ldW1(1, vfB);
#pragma unroll
  for (int ct = 0; ct < 2; ++ct) xmkC[ct] = *(const f16x8*)&xs[(ct * 32 + l31) * 56];

  for (int g = 0; g < 5; ++g) {
    int gn = (g < 4) ? g + 1 : 4;
#pragma unroll
    for (int ct = 0; ct < 2; ++ct)
      xmkN[ct] = *(const f16x8*)&xs[(ct * 32 + l31) * 56 + gn * 8];
#pragma unroll
    for (int jj = 0; jj < 8; jj += 2) {
      int m = g * 8 + jj;
#pragma unroll
      for (int ct = 0; ct < 2; ++ct) {
        _Float16 xm = xmkC[ct][jj];
#pragma unroll
        for (int ks = 0; ks < 4; ++ks) {
          f16x8 bz = hf[ct][ks] * xm;
          acc1[ct] = __builtin_amdgcn_mfma_f32_32x32x16_f16(vfA[ks], bz, acc1[ct], 0, 0, 0);
        }
      }
      { int mp = (m + 2 > 39) ? 39 : m + 2; ldW1(mp, vfA); }
#pragma unroll
      for (int ct = 0; ct < 2; ++ct) {
        _Float16 xm = xmkC[ct][jj + 1];
#pragma unroll
        for (int ks = 0; ks < 4; ++ks) {
          f16x8 bz = hf[ct][ks] * xm;
          acc1[ct] = __builtin_amdgcn_mfma_f32_32x32x16_f16(vfB[ks], bz, acc1[ct], 0, 0, 0);
        }
      }
      { int mp = (m + 3 > 39) ? 39 : m + 3; ldW1(mp, vfB); }
    }
    xmkC[0] = xmkN[0]; xmkC[1] = xmkN[1];
  }

  // ---- combine K-halves, then bias+relu+d-sum -> out[ch 128..255] ----
  __syncthreads();
  if (kh == 1) {
#pragma unroll
    for (int ct = 0; ct < 2; ++ct)
#pragma unroll
      for (int reg = 0; reg < 16; ++reg) {
        int row = (reg & 3) + 8 * (reg >> 2) + 4 * hi;
        red[(rt * 32 + row) * 66 + ct * 32 + l31] = acc1[ct][reg];
      }
  }
  __syncthreads();
  if (kh == 0) {
#pragma unroll
    for (int ct = 0; ct < 2; ++ct)
#pragma unroll
      for (int reg = 0; reg < 16; ++reg) {
        int row = (reg & 3) + 8 * (reg >> 2) + 4 * hi;
        int o = rt * 32 + row;  // 0..127
        float v = acc1[ct][reg] + red[(rt * 32 + row) * 66 + ct * 32 + l31];
        v = fmaxf(v + b1[o], 0.f);
        v += __shfl_xor(v, 1); v += __shfl_xor(v, 2); v += __shfl_xor(v, 4);
        v += __shfl_xor(v, 8); v += __shfl_xor(v, 16);
        if (l31 == 0) out[(bb + ct) * 256 + 128 + o] = v;
      }
  }
}

extern "C" void kernel_launch(void* const* d_in, const int* in_sizes, int n_in,
                              void* d_out, int out_size, void* d_ws, size_t ws_size,
                              hipStream_t stream) {
  const float* x  = (const float*)d_in[0];
  const float* w0 = (const float*)d_in[1];
  const float* b0 = (const float*)d_in[2];
  const float* w1 = (const float*)d_in[3];
  const float* b1 = (const float*)d_in[4];
  float* out = (float*)d_out;

  _Float16* w0r = (_Float16*)d_ws;             // 40*8*3*512 f16 = 983040 B
  _Float16* w1r = w0r + 40 * 8 * 3 * 512;      // 40*2*4*4*512 f16 = 1310720 B

  prep_kernel<<<256, 256, 0, stream>>>(w0, w1, w0r, w1r);
  cin_kernel<<<NBLK, THREADS, 0, stream>>>(x, w0r, b0, w1r, b1, out);
}

// Round 10
// 87.724 us; speedup vs baseline: 1.3225x; 1.3225x over previous
//
#include <hip/hip_runtime.h>

// CIN (xDeepFM) fused kernel for MI355X (gfx950), round 10.
// r7 microstructure (16x16x32 f16, in-register z, 4-deep L0 / 2-deep L1
// prefetch, reassociated L1) kept verbatim per wave. New:
//  - 1024-thr blocks, NB=4, grid=256 (1 block/CU): two 8-wave FAMILIES per
//    block run identical code on cols 0-63 / 64-127, reading the SAME weight
//    addresses at the same pace -> family 2 hits L1 -> L2 traffic ~halves.
//  - L1 m-loop staggered per XCD-resident block (phase=((bid>>3)&7)*5, mod 40;
//    sum over m is order-invariant) -> de-convoys L2 banks within an XCD.

typedef _Float16 f16x8 __attribute__((ext_vector_type(8)));
typedef float f32x4 __attribute__((ext_vector_type(4)));

#define NB 4
#define NBLK 256
#define THREADS 1024
#define K0P 52   // padded L0 steps (s=50,51 zero weights for prefetch overrun)
#define M1P 42

__global__ __launch_bounds__(256) void prep_kernel(
    const float* __restrict__ w0, const float* __restrict__ w1,
    _Float16* __restrict__ w0c, _Float16* __restrict__ w1c) {
  int stride = gridDim.x * blockDim.x;
  int tid = blockIdx.x * blockDim.x + threadIdx.x;
  // w0c: [s<52][w8<8][mt<2][l15<16][lhi<4][j<8]; row o=w8*32+mt*16+l15,
  // k-index ip = s*32+lhi*8+j with reorder i' = m*40+n (n<39 valid, else 0).
  const int n0 = K0P * 8192;
  for (int idx = tid; idx < n0; idx += stride) {
    int j = idx & 7, lhi = (idx >> 3) & 3, l15 = (idx >> 5) & 15;
    int mt = (idx >> 9) & 1, w8 = (idx >> 10) & 7, s = idx >> 13;
    int o = w8 * 32 + mt * 16 + l15;
    int ip = s * 32 + lhi * 8 + j;
    float v = 0.f;
    if (ip < 1560) {
      unsigned m = (unsigned)ip / 40u;
      unsigned n = (unsigned)ip - m * 40u;
      if (n < 39u) v = w0[o * 1521 + m * 39 + n];
    }
    w0c[idx] = (_Float16)v;
  }
  // w1c: [m<42][kh<2][rt<4][kf<2][mt<2][l15<16][lhi<4][j<8];
  //      row o=rt*32+mt*16+l15, k = kh*64+kf*32+lhi*8+j (within W1_m).
  const int n1 = M1P * 16384;
  for (int idx = tid; idx < n1; idx += stride) {
    int j = idx & 7, lhi = (idx >> 3) & 3, l15 = (idx >> 5) & 15;
    int mt = (idx >> 9) & 1, kf = (idx >> 10) & 1, rt = (idx >> 11) & 3;
    int kh = (idx >> 13) & 1, m = idx >> 14;
    int o = rt * 32 + mt * 16 + l15;
    int k = kh * 64 + kf * 32 + lhi * 8 + j;
    float v = (m < 39) ? w1[o * 4992 + m * 128 + k] : 0.f;
    w1c[idx] = (_Float16)v;
  }
}

__global__ __launch_bounds__(1024, 1) void cin_kernel(
    const float* __restrict__ x,
    const _Float16* __restrict__ w0c, const float* __restrict__ b0,
    const _Float16* __restrict__ w1c, const float* __restrict__ b1,
    float* __restrict__ out) {
  // LDS: 10240 + 34816 + 66560 = 111616 B -> 1 block/CU
  __shared__ __align__(16) _Float16 xs[128 * 40];      // [c=(b,d)][40], col 39 = 0
  __shared__ __align__(16) _Float16 h1[2 * 64 * 136];  // per-family [c][136]
  __shared__ __align__(16) float red[2 * 4 * 32 * 65]; // per-family K-half exchange

  const int t = threadIdx.x;
  const int bb = blockIdx.x * NB;
  const int w = t >> 6;          // wave 0..15
  const int fam = w >> 3;        // batch family: cols fam*64 .. fam*64+63
  const int w8 = w & 7;          // wave within family
  const int l15 = t & 15;
  const int lhi = (t >> 4) & 3;
  const int lane_off = ((l15 << 2) | lhi) << 3;

  int xrow[4];
#pragma unroll
  for (int nt = 0; nt < 4; ++nt) xrow[nt] = (fam * 64 + nt * 16 + l15) * 40;

  // ---- stage x -> xs[c=(b,d)][m], f16 ----
  for (int idx = t; idx < NB * 39 * 32; idx += THREADS) {
    int b = idx / 1248; int rem = idx - b * 1248;
    int m = rem >> 5; int d = rem & 31;
    xs[(b * 32 + d) * 40 + m] = (_Float16)x[(bb + b) * 1248 + rem];
  }
  if (t < 128) xs[t * 40 + 39] = (_Float16)0.f;  // zero the m=39 pad
  __syncthreads();

  // ================= LAYER 0 (barrier-free K-loop, 32 rows/wave) =================
  f32x4 acc[2][4] = {};
  const _Float16* p0 = w0c + w8 * 1024 + lane_off;

  auto loadA0 = [&](int s, f16x8 (&af)[2]) {
    const _Float16* p = p0 + s * 8192;
    af[0] = *(const f16x8*)(p);
    af[1] = *(const f16x8*)(p + 512);
  };
  auto zfr = [&](int s, f16x8 (&bz)[4]) {
    unsigned i0 = (unsigned)(s * 32) + (unsigned)lhi * 8u;
    unsigned m = (i0 * 52429u) >> 21;   // i0/40 (exact for i0 < 2^16)
    unsigned nb = i0 - m * 40u;
#pragma unroll
    for (int nt = 0; nt < 4; ++nt) {
      _Float16 xm = xs[xrow[nt] + m];                 // m==39 -> 0
      f16x8 xn = *(const f16x8*)&xs[xrow[nt] + nb];   // 16B-aligned (80B rows)
      bz[nt] = xn * xm;                               // v_pk_mul_f16
    }
  };
  auto comp0 = [&](f16x8 (&af)[2], f16x8 (&bz)[4]) {
#pragma unroll
    for (int mt = 0; mt < 2; ++mt)
#pragma unroll
      for (int nt = 0; nt < 4; ++nt)
        acc[mt][nt] = __builtin_amdgcn_mfma_f32_16x16x32_f16(af[mt], bz[nt], acc[mt][nt], 0, 0, 0);
  };

  {
    f16x8 af0[2], af1[2], af2[2], af3[2];
    loadA0(0, af0); loadA0(1, af1); loadA0(2, af2); loadA0(3, af3);
    for (int s = 0; s < 48; s += 4) {
      f16x8 bz[4];
      zfr(s + 0, bz); comp0(af0, bz); loadA0(s + 4, af0);
      zfr(s + 1, bz); comp0(af1, bz); loadA0(s + 5, af1);
      zfr(s + 2, bz); comp0(af2, bz); loadA0(s + 6, af2);
      zfr(s + 3, bz); comp0(af3, bz); loadA0(s + 7, af3);
    }
    f16x8 bz[4];
    zfr(48, bz); comp0(af0, bz);
    zfr(49, bz); comp0(af1, bz);
  }

  // ---- epilogue 0: bias+relu; o<128 -> h1a LDS; o>=128 -> d-sum -> out[ch 0..127]
  if (w8 < 4) {
#pragma unroll
    for (int mt = 0; mt < 2; ++mt) {
#pragma unroll
      for (int nt = 0; nt < 4; ++nt) {
        int c = nt * 16 + l15;
        int hbase = fam * 8704 + c * 136;
#pragma unroll
        for (int r = 0; r < 4; ++r) {
          int o = w8 * 32 + mt * 16 + lhi * 4 + r;
          float v = fmaxf(acc[mt][nt][r] + b0[o], 0.f);
          h1[hbase + o] = (_Float16)v;
        }
      }
    }
  } else {
#pragma unroll
    for (int mt = 0; mt < 2; ++mt) {
#pragma unroll
      for (int r = 0; r < 4; ++r) {
        int o = w8 * 32 + mt * 16 + lhi * 4 + r;  // 128..255
        float bias = b0[o];
        float sb0 = 0.f, sb1 = 0.f;
#pragma unroll
        for (int nt = 0; nt < 4; ++nt) {
          float v = fmaxf(acc[mt][nt][r] + bias, 0.f);
          v += __shfl_xor(v, 1); v += __shfl_xor(v, 2);
          v += __shfl_xor(v, 4); v += __shfl_xor(v, 8);
          if (nt < 2) sb0 += v; else sb1 += v;
        }
        if (l15 == 0) {
          out[(bb + fam * 2 + 0) * 256 + (o - 128)] = sb0;
          out[(bb + fam * 2 + 1) * 256 + (o - 128)] = sb1;
        }
      }
    }
  }
  __syncthreads();  // h1a visible

  // ============ LAYER 1 (reassociated; per family: 4 row-groups x 2 K-halves) ====
  const int rt = w8 >> 1;
  const int kh = w8 & 1;

  f16x8 hf[2][4];
#pragma unroll
  for (int kf = 0; kf < 2; ++kf)
#pragma unroll
    for (int nt = 0; nt < 4; ++nt)
      hf[kf][nt] = *(const f16x8*)&h1[fam * 8704 + (nt * 16 + l15) * 136 + (kh * 2 + kf) * 32 + lhi * 8];

  f32x4 acc2[2][4] = {};
  const _Float16* p1 = w1c + (kh * 4 + rt) * 2048 + lane_off;

  float xmv[2][4];
  auto xmvld = [&](int m, int b) {
#pragma unroll
    for (int nt = 0; nt < 4; ++nt) xmv[b][nt] = (float)xs[xrow[nt] + m];
  };
  auto loadA1 = [&](int m, f16x8 (&wf)[2][2]) {
    const _Float16* p = p1 + m * 16384;
    wf[0][0] = *(const f16x8*)(p);
    wf[0][1] = *(const f16x8*)(p + 512);
    wf[1][0] = *(const f16x8*)(p + 1024);
    wf[1][1] = *(const f16x8*)(p + 1536);
  };
  auto computeM = [&](f16x8 (&wf)[2][2], float (&xv)[4]) {
#pragma unroll
    for (int mt = 0; mt < 2; ++mt)
#pragma unroll
      for (int nt = 0; nt < 4; ++nt) {
        f32x4 Y = __builtin_amdgcn_mfma_f32_16x16x32_f16(wf[0][mt], hf[0][nt],
                                                         (f32x4){0.f, 0.f, 0.f, 0.f}, 0, 0, 0);
        Y = __builtin_amdgcn_mfma_f32_16x16x32_f16(wf[1][mt], hf[1][nt], Y, 0, 0, 0);
        acc2[mt][nt] += Y * xv[nt];   // v_pk_fma_f32
      }
  };

  {
    // m-stagger: blocks co-resident on one XCD start at different phases.
    // Sum over m is order-invariant; m=39 contributes 0 (xs pad + zero weights).
    int bph = ((blockIdx.x >> 3) & 7) * 5;
    int me = bph;
    int mo = bph + 1; if (mo >= 40) mo -= 40;
    f16x8 wfA[2][2], wfB[2][2];
    loadA1(me, wfA);
    loadA1(mo, wfB);
    xmvld(me, 0);
    for (int it = 0; it < 20; ++it) {
      xmvld(mo, 1);
      computeM(wfA, xmv[0]);
      me += 2; if (me >= 40) me -= 40;
      loadA1(me, wfA);
      if (it < 19) xmvld(me, 0);
      computeM(wfB, xmv[1]);
      mo += 2; if (mo >= 40) mo -= 40;
      loadA1(mo, wfB);
    }
  }

  // ---- combine K-halves via LDS: kh==1 writes, kh==0 adds ----
  __syncthreads();
  if (kh == 1) {
#pragma unroll
    for (int mt = 0; mt < 2; ++mt)
#pragma unroll
      for (int nt = 0; nt < 4; ++nt)
#pragma unroll
        for (int r = 0; r < 4; ++r) {
          int row = mt * 16 + lhi * 4 + r, c = nt * 16 + l15;
          red[fam * 8320 + (rt * 32 + row) * 65 + c] = acc2[mt][nt][r];
        }
  }
  __syncthreads();
  if (kh == 0) {
#pragma unroll
    for (int mt = 0; mt < 2; ++mt)
#pragma unroll
      for (int nt = 0; nt < 4; ++nt)
#pragma unroll
        for (int r = 0; r < 4; ++r) {
          int row = mt * 16 + lhi * 4 + r, c = nt * 16 + l15;
          acc2[mt][nt][r] += red[fam * 8320 + (rt * 32 + row) * 65 + c];
        }

    // ---- epilogue 1: bias+relu, d-sum -> out[ch 128..255]
#pragma unroll
    for (int mt = 0; mt < 2; ++mt) {
#pragma unroll
      for (int r = 0; r < 4; ++r) {
        int o = rt * 32 + mt * 16 + lhi * 4 + r;  // 0..127
        float bias = b1[o];
        float sb0 = 0.f, sb1 = 0.f;
#pragma unroll
        for (int nt = 0; nt < 4; ++nt) {
          float v = fmaxf(acc2[mt][nt][r] + bias, 0.f);
          v += __shfl_xor(v, 1); v += __shfl_xor(v, 2);
          v += __shfl_xor(v, 4); v += __shfl_xor(v, 8);
          if (nt < 2) sb0 += v; else sb1 += v;
        }
        if (l15 == 0) {
          out[(bb + fam * 2 + 0) * 256 + 128 + o] = sb0;
          out[(bb + fam * 2 + 1) * 256 + 128 + o] = sb1;
        }
      }
    }
  }
}

extern "C" void kernel_launch(void* const* d_in, const int* in_sizes, int n_in,
                              void* d_out, int out_size, void* d_ws, size_t ws_size,
                              hipStream_t stream) {
  const float* x  = (const float*)d_in[0];
  const float* w0 = (const float*)d_in[1];
  const float* b0 = (const float*)d_in[2];
  const float* w1 = (const float*)d_in[3];
  const float* b1 = (const float*)d_in[4];
  float* out = (float*)d_out;

  _Float16* w0c = (_Float16*)d_ws;             // 52*8192  f16 = 851968 B
  _Float16* w1c = w0c + K0P * 8192;            // 42*16384 f16 = 1376256 B

  prep_kernel<<<256, 256, 0, stream>>>(w0, w1, w0c, w1c);
  cin_kernel<<<NBLK, THREADS, 0, stream>>>(x, w0c, b0, w1c, b1, out);
}